// Round 16
// baseline (2951.669 us; speedup 1.0000x reference)
//
#include <hip/hip_runtime.h>
#include <cstddef>

#define NB 32
#define NT 512
#define ND 1024
#define NH 1024
#define NG 4096   // 4*NH
#define GRID 256  // block = 4 units x BOTH groups; 8 waves K-split-8

typedef unsigned short ushortT;
typedef unsigned long long u64;
typedef __attribute__((ext_vector_type(8))) short short8;   // 8 bf16 = 4 VGPR
typedef __attribute__((ext_vector_type(4))) float f32x4;
typedef __attribute__((ext_vector_type(4))) unsigned uint4v;

#define GLL16(g, l) __builtin_amdgcn_global_load_lds(                      \
    (const __attribute__((address_space(1))) void*)(g),                    \
    (__attribute__((address_space(3))) void*)(l), 16, 0, 0)

__device__ __forceinline__ ushortT f2bf(float f) {
    union { float f; unsigned u; } v; v.f = f;
    unsigned r = v.u + 0x7FFFu + ((v.u >> 16) & 1u);   // RNE
    return (ushortT)(r >> 16);
}
__device__ __forceinline__ float bf2f(ushortT u) {
    union { unsigned u; float f; } v; v.u = (unsigned)u << 16; return v.f;
}

__device__ __forceinline__ float pick4(float a0, float a1, float a2, float a3, int s) {
    float lo = (s & 1) ? a1 : a0;
    float hi = (s & 1) ? a3 : a2;
    return (s & 2) ? hi : lo;
}

__device__ __forceinline__ float fsigmoid(float x) {
    return __builtin_amdgcn_rcpf(1.f + __expf(-x));
}
__device__ __forceinline__ float ftanh(float x) {
    float xc = fminf(fmaxf(x, -15.f), 15.f);
    float e  = __expf(-2.f * xc);
    return (1.f - e) * __builtin_amdgcn_rcpf(1.f + e);
}

// ---------------------------------------------------------------------------
__global__ __launch_bounds__(256) void cast_bf16(const float* __restrict__ src,
                                                 ushortT* __restrict__ dst, int n4)
{
    int i = blockIdx.x * 256 + threadIdx.x;
    if (i < n4) {
        float4 v = ((const float4*)src)[i];
        ushort4 o;
        o.x = f2bf(v.x); o.y = f2bf(v.y); o.z = f2bf(v.z); o.w = f2bf(v.w);
        ((ushort4*)dst)[i] = o;
    }
}

// ---------------------------------------------------------------------------
// transpose + cast: src f32 [1024][4096] -> dst bf16 [4096][1024]
// permute=1 remaps dst row n=(g*1024+j) -> (j>>2)*16 + g*4 + (j&3)
// ---------------------------------------------------------------------------
__global__ __launch_bounds__(256) void transpose_cast(
    const float* __restrict__ src, ushortT* __restrict__ dst, int permute)
{
    __shared__ ushortT tile[64][66];
    const int c0 = blockIdx.x * 64, r0 = blockIdx.y * 64;
    const int cc = threadIdx.x & 63, rq = threadIdx.x >> 6;
    #pragma unroll
    for (int ps = 0; ps < 16; ++ps) {
        int r = ps * 4 + rq;
        tile[cc][r] = f2bf(src[(size_t)(r0 + r) * NG + c0 + cc]);
    }
    __syncthreads();
    #pragma unroll
    for (int ps = 0; ps < 16; ++ps) {
        int cl = ps * 4 + rq;
        int n  = c0 + cl;
        int drow = permute ? ((((n & 1023) >> 2) << 4) | ((n >> 10) << 2) | (n & 3))
                           : n;
        dst[(size_t)drow * 1024 + r0 + cc] = tile[cl][cc];
    }
}

// ---------------------------------------------------------------------------
// xW GEMM, bf16 MFMA, global_load_lds staging (proven r7-r15).
// Epilogue: bf16 + permuted cols:  xwpb[(trel*NB+b)][perm(n)]
// ---------------------------------------------------------------------------
__global__ __launch_bounds__(256) void gemm_xw_mfma(
    const ushortT* __restrict__ xb,   // [NB*NT][ND] bf16
    const ushortT* __restrict__ wxT,  // [NG][ND]    bf16
    const float* __restrict__ bias,
    ushortT* __restrict__ XWPb,       // [Tc*NB][NG] bf16, permuted cols
    int t0, int Tc, int tcsh)
{
    __shared__ ushortT As[128 * 32];
    __shared__ ushortT Bs[128 * 32];

    const int tid  = threadIdx.x;
    const int lane = tid & 63;
    const int wv   = tid >> 6;
    const int wr   = wv >> 1, wc = wv & 1;
    const int n0   = blockIdx.x * 128;
    const int m0   = blockIdx.y * 128;

    const int c1 = tid, c2 = tid + 256;
    const int rm1 = m0 + (c1 >> 2), rm2 = m0 + (c2 >> 2);
    const int xr1 = ((rm1 >> tcsh) * NT) + t0 + (rm1 & (Tc - 1));
    const int xr2 = ((rm2 >> tcsh) * NT) + t0 + (rm2 & (Tc - 1));
    const ushortT* ap1 = xb + (size_t)xr1 * ND + (c1 & 3) * 8;
    const ushortT* ap2 = xb + (size_t)xr2 * ND + (c2 & 3) * 8;
    const ushortT* bp1 = wxT + (size_t)(n0 + (c1 >> 2)) * ND + (c1 & 3) * 8;
    const ushortT* bp2 = wxT + (size_t)(n0 + (c2 >> 2)) * ND + (c2 & 3) * 8;

    f32x4 acc[4][4];
    #pragma unroll
    for (int m = 0; m < 4; ++m)
        #pragma unroll
        for (int n = 0; n < 4; ++n) acc[m][n] = (f32x4){0.f, 0.f, 0.f, 0.f};

    const int arow_base = (wr * 64 + (lane & 15)) * 32 + (lane >> 4) * 8;
    const int brow_base = (wc * 64 + (lane & 15)) * 32 + (lane >> 4) * 8;

    for (int k0 = 0; k0 < ND; k0 += 32) {
        __syncthreads();
        GLL16(ap1 + k0, &As[c1 * 8]);
        GLL16(ap2 + k0, &As[c2 * 8]);
        GLL16(bp1 + k0, &Bs[c1 * 8]);
        GLL16(bp2 + k0, &Bs[c2 * 8]);
        __syncthreads();
        short8 af[4], bf[4];
        #pragma unroll
        for (int m = 0; m < 4; ++m)
            af[m] = *(const short8*)&As[arow_base + m * 16 * 32];
        #pragma unroll
        for (int n = 0; n < 4; ++n)
            bf[n] = *(const short8*)&Bs[brow_base + n * 16 * 32];
        #pragma unroll
        for (int m = 0; m < 4; ++m)
            #pragma unroll
            for (int n = 0; n < 4; ++n)
                acc[m][n] = __builtin_amdgcn_mfma_f32_16x16x32_bf16(
                    af[m], bf[n], acc[m][n], 0, 0, 0);
    }

    #pragma unroll
    for (int n = 0; n < 4; ++n) {
        int col = n0 + wc * 64 + n * 16 + (lane & 15);
        int pc  = (((col & 1023) >> 2) << 4) | ((col >> 10) << 2) | (col & 3);
        float bs = bias[col];
        #pragma unroll
        for (int m = 0; m < 4; ++m) {
            #pragma unroll
            for (int r = 0; r < 4; ++r) {
                int rm = m0 + wr * 64 + m * 16 + (lane >> 4) * 4 + r;
                int b  = rm >> tcsh, tr = rm & (Tc - 1);
                XWPb[((size_t)tr * NB + b) * NG + pc] = f2bf(acc[m][n][r] + bs);
            }
        }
    }
}

// ---------------------------------------------------------------------------
// Persistent LSTM recurrence, TWO-GROUP SOFTWARE PIPELINE.
// 256 blocks; block blk owns hidden units [4blk,4blk+4) (= permuted cols
// [16blk,16blk+16)) for BOTH batch groups (A = rows 0-15, B = rows 16-31).
// Per cycle (one step of both groups):
//   phase A: pollA -> direct A-loads -> 4 MFMAs (K-split-8) -> redA write
//            -> barrier -> waves0-3: reduce+act+h-store+vmcnt+flagA
//   phase B: identical on group B.
// While a block computes B, A's h/flag stores propagate -> A's next poll
// finds them visible (latency hidden by the other group's compute).
// Sync protocol per group = r9-proven: per-(block,storewave) flags, wave-
// local vmcnt before flag, consumer wave polls the 128 flags of its K-slice
// (2/lane u64); the 8 waves jointly cover all 1024 group flags and the
// barrier orders polls before stores => double-buffer overwrite safety.
// ---------------------------------------------------------------------------
__global__ __launch_bounds__(512) void lstm_persist(
    const ushortT* __restrict__ XWPb,  // [Tc*NB][NG] bf16, permuted cols
    const ushortT* __restrict__ whpT,  // [4096][1024] permuted bf16
    unsigned* __restrict__ hb0,        // [32][512] dwords (2xbf16), parity 0
    unsigned* __restrict__ hb1,        // parity 1 (h0 here)
    const float* __restrict__ cinit,
    float* __restrict__ cT,
    float* __restrict__ out,           // [NB][NT][NH] f32
    float* __restrict__ hT,
    unsigned* __restrict__ flags,      // [2 grp][1024], zeroed per launch
    int t0, int Tc)
{
    __shared__ float red[2][8 * 16 * 17];   // 17.4 KB: [phase][(w*16+row)*17+col]

    const int tid  = threadIdx.x;
    const int lane = tid & 63;
    const int w    = tid >> 6;          // K-split wave: units [128w,128w+128)
    const int blk  = blockIdx.x;        // 0..255

    const int lo = lane & 15;
    const int hi = lane >> 4;

    // Wh register residency: 16 permuted cols x wave's K=128 (16 VGPR)
    short8 Bf[4];
    #pragma unroll
    for (int ks = 0; ks < 4; ++ks)
        Bf[ks] = *(const short8*)(whpT
            + (size_t)(blk * 16 + lo) * NH + w * 128 + ks * 32 + hi * 8);

    // reduce/activation roles (waves 0-3 only: tid < 256)
    const int rrow = (tid >> 4) & 15;   // row within group (valid tid<256)
    const int col  = tid & 15;          // permuted col within block
    const int gq   = col >> 2;
    const int jj   = col & 3;
    const int j    = blk * 4 + jj;      // hidden unit

    float cregA = 0.f, cregB = 0.f;
    if (tid < 256) {
        cregA = cinit[(size_t)rrow * NH + j];
        cregB = cinit[(size_t)(16 + rrow) * NH + j];
    }

    // direct A-frag source (u64 idx): row lo, units 128w + ks*32 + hi*8
    const size_t abase64 = (size_t)lo * 256 + 32 * w + 2 * hi;

    // flag pointers: wave w consumes units [128w,+128) = blocks [32w,32w+32)
    // x 4 store-waves -> flag indices [128w, 128w+128), 2/lane as u64
    const u64* fpollA = (const u64*)(flags + 0 * 1024 + 128 * w + 2 * lane);
    const u64* fpollB = (const u64*)(flags + 1 * 1024 + 128 * w + 2 * lane);
    unsigned* const fmineA = flags + 0 * 1024 + blk * 4 + w;   // valid w<4
    unsigned* const fmineB = flags + 1 * 1024 + blk * 4 + w;

    ushortT xvrA = 0, xvrB = 0;
    if (tid < 256) {
        xvrA = XWPb[(size_t)rrow * NG + blk * 16 + col];
        xvrB = XWPb[(size_t)(16 + rrow) * NG + blk * 16 + col];
    }

    const int tend = t0 + Tc;
    for (int t = t0; t < tend; ++t) {
        const int trel = t - t0;
        const unsigned* hRg = (t & 1) ? hb0 : hb1;   // h_{t-1}
        unsigned*       hWg = (t & 1) ? hb1 : hb0;   // h_t

        #pragma unroll
        for (int ph = 0; ph < 2; ++ph) {
            const unsigned* hR = hRg + ph * 8192;
            unsigned*       hW = hWg + ph * 8192;
            const u64* fp = ph ? fpollB : fpollA;

            // ---- poll this wave's producers (skip at trel==0) ----
            if (trel) {
                const unsigned tgt = (unsigned)trel;
                for (int it = 0; it < (1 << 17); ++it) {
                    u64 v = __hip_atomic_load(fp, __ATOMIC_RELAXED,
                                              __HIP_MEMORY_SCOPE_AGENT);
                    bool ok = ((unsigned)v >= tgt) && ((unsigned)(v >> 32) >= tgt);
                    if (__all(ok)) break;
                }
            }

            // ---- direct A-frag loads (agent 8B atomics) ----
            const u64* ap = (const u64*)hR + abase64;
            u64 q0, q1;
            uint4v d0, d1, d2, d3;
            q0 = __hip_atomic_load(ap + 0,  __ATOMIC_RELAXED, __HIP_MEMORY_SCOPE_AGENT);
            q1 = __hip_atomic_load(ap + 1,  __ATOMIC_RELAXED, __HIP_MEMORY_SCOPE_AGENT);
            d0 = (uint4v){(unsigned)q0, (unsigned)(q0 >> 32), (unsigned)q1, (unsigned)(q1 >> 32)};
            q0 = __hip_atomic_load(ap + 8,  __ATOMIC_RELAXED, __HIP_MEMORY_SCOPE_AGENT);
            q1 = __hip_atomic_load(ap + 9,  __ATOMIC_RELAXED, __HIP_MEMORY_SCOPE_AGENT);
            d1 = (uint4v){(unsigned)q0, (unsigned)(q0 >> 32), (unsigned)q1, (unsigned)(q1 >> 32)};
            q0 = __hip_atomic_load(ap + 16, __ATOMIC_RELAXED, __HIP_MEMORY_SCOPE_AGENT);
            q1 = __hip_atomic_load(ap + 17, __ATOMIC_RELAXED, __HIP_MEMORY_SCOPE_AGENT);
            d2 = (uint4v){(unsigned)q0, (unsigned)(q0 >> 32), (unsigned)q1, (unsigned)(q1 >> 32)};
            q0 = __hip_atomic_load(ap + 24, __ATOMIC_RELAXED, __HIP_MEMORY_SCOPE_AGENT);
            q1 = __hip_atomic_load(ap + 25, __ATOMIC_RELAXED, __HIP_MEMORY_SCOPE_AGENT);
            d3 = (uint4v){(unsigned)q0, (unsigned)(q0 >> 32), (unsigned)q1, (unsigned)(q1 >> 32)};

            short8 A0 = *(short8*)&d0;
            short8 A1 = *(short8*)&d1;
            short8 A2 = *(short8*)&d2;
            short8 A3 = *(short8*)&d3;

            // ---- 4 MFMAs (2 chains) over this wave's K-slice ----
            f32x4 acc0 = (f32x4){0.f, 0.f, 0.f, 0.f};
            f32x4 acc1 = (f32x4){0.f, 0.f, 0.f, 0.f};
            acc0 = __builtin_amdgcn_mfma_f32_16x16x32_bf16(A0, Bf[0], acc0, 0, 0, 0);
            acc1 = __builtin_amdgcn_mfma_f32_16x16x32_bf16(A1, Bf[1], acc1, 0, 0, 0);
            acc0 = __builtin_amdgcn_mfma_f32_16x16x32_bf16(A2, Bf[2], acc0, 0, 0, 0);
            acc1 = __builtin_amdgcn_mfma_f32_16x16x32_bf16(A3, Bf[3], acc1, 0, 0, 0);

            #pragma unroll
            for (int r = 0; r < 4; ++r)
                red[ph][(w * 16 + hi * 4 + r) * 17 + lo] = acc0[r] + acc1[r];
            __syncthreads();   // red[ph] visible; all polls of this phase done

            // ---- epilogue: waves 0-3 only ----
            if (tid < 256) {
                float xv = bf2f(ph ? xvrB : xvrA);
                float g = xv;
                #pragma unroll
                for (int wv = 0; wv < 8; ++wv)
                    g += red[ph][(wv * 16 + rrow) * 17 + col];

                float g4  = __shfl_xor(g, 4);
                float g8  = __shfl_xor(g, 8);
                float g12 = __shfl_xor(g, 12);

                float gi = pick4(g, g4, g8, g12, gq);
                float gf = pick4(g, g4, g8, g12, gq ^ 1);
                float gg = pick4(g, g4, g8, g12, gq ^ 2);
                float go = pick4(g, g4, g8, g12, gq ^ 3);

                float iv = fsigmoid(gi);
                float fv = fsigmoid(gf);
                float gv = ftanh(gg);
                float ov = fsigmoid(go);
                float creg = ph ? cregB : cregA;
                float cn = fv * creg + iv * gv;
                float hn = ov * ftanh(cn);
                if (ph) cregB = cn; else cregA = cn;

                float p2 = __shfl_xor(hn, 1);   // partner unit j^1
                const bool wl = (gq == 0) && ((col & 1) == 0);
                const int brow = ph * 16 + rrow;
                if (wl) {
                    unsigned pair = (unsigned)f2bf(hn) | ((unsigned)f2bf(p2) << 16);
                    __hip_atomic_store(&hW[rrow * 512 + 2 * blk + (col >> 1)], pair,
                                       __ATOMIC_RELAXED, __HIP_MEMORY_SCOPE_AGENT);
                    *(float2*)&out[((size_t)brow * NT + t) * NH + j] = make_float2(hn, p2);
                }
                if (t == tend - 1 && gq == 0) {
                    if (t == NT - 1) hT[(size_t)brow * NH + j] = hn;
                    cT[(size_t)brow * NH + j] = cn;
                }
                // wave-local drain of h stores, then per-wave flag publish
                if (t != tend - 1) {
                    asm volatile("s_waitcnt vmcnt(0)" ::: "memory");
                    if (lane == 0)
                        __hip_atomic_store(ph ? fmineB : fmineA,
                                           (unsigned)(trel + 1),
                                           __ATOMIC_RELAXED, __HIP_MEMORY_SCOPE_AGENT);
                }
            }
        }

        // off-critical-path: next-step xW prefetch
        if (t != tend - 1 && tid < 256) {
            xvrA = XWPb[((size_t)(trel + 1) * NB + rrow) * NG + blk * 16 + col];
            xvrB = XWPb[((size_t)(trel + 1) * NB + 16 + rrow) * NG + blk * 16 + col];
        }
    }
}

// ---------------------------------------------------------------------------
extern "C" void kernel_launch(void* const* d_in, const int* in_sizes, int n_in,
                              void* d_out, int out_size, void* d_ws, size_t ws_size,
                              hipStream_t stream) {
    const float* x    = (const float*)d_in[0];
    const float* c0   = (const float*)d_in[1];
    const float* h0   = (const float*)d_in[2];
    const float* Wx   = (const float*)d_in[3];
    const float* Wh   = (const float*)d_in[4];
    const float* bias = (const float*)d_in[5];

    float* out = (float*)d_out;
    float* cT  = out + (size_t)NB * NT * NH;
    float* hT  = cT + (size_t)NB * NH;

    // ws: xb 33.5MB | wxT 8.4MB | whpT 8.4MB | hb0 64KB | hb1 64KB | flags 8KB | xwpb
    ushortT* xb   = (ushortT*)d_ws;
    ushortT* wxT  = xb  + (size_t)NB * NT * ND;
    ushortT* whpT = wxT + (size_t)NG * ND;
    unsigned* hb0 = (unsigned*)(whpT + (size_t)NG * NH);
    unsigned* hb1 = hb0 + NB * NH / 2;
    unsigned* flags = hb1 + NB * NH / 2;
    ushortT* xwpb = (ushortT*)(flags + 2 * 1024);

    const size_t fixed = ((size_t)NB * NT * ND + (size_t)NG * ND + (size_t)NG * NH
                          + 2 * NB * NH) * sizeof(ushortT) + 2 * 1024 * 4 + 256;
    int Tc = 512;
    while (Tc > 4 && fixed + (size_t)NB * Tc * NG * sizeof(ushortT) > ws_size)
        Tc >>= 1;
    int tcsh = 31 - __builtin_clz(Tc);

    cast_bf16<<<(NB * NT * ND / 4 + 255) / 256, 256, 0, stream>>>(x, xb, NB * NT * ND / 4);
    // h0 -> hb1 (parity-1 buffer: hR at t=0)
    cast_bf16<<<(NB * NH / 4 + 255) / 256, 256, 0, stream>>>(h0, (ushortT*)hb1, NB * NH / 4);
    transpose_cast<<<dim3(64, 16), 256, 0, stream>>>(Wx, wxT, 0);
    transpose_cast<<<dim3(64, 16), 256, 0, stream>>>(Wh, whpT, 1);

    for (int t0 = 0; t0 < NT; t0 += Tc) {
        dim3 g(NG / 128, (NB * Tc) / 128);
        gemm_xw_mfma<<<g, 256, 0, stream>>>(xb, wxT, bias, xwpb, t0, Tc, tcsh);
        hipMemsetAsync(flags, 0, 2 * 1024 * sizeof(unsigned), stream);
        lstm_persist<<<GRID, 512, 0, stream>>>(
            xwpb, whpT, hb0, hb1,
            (t0 == 0) ? c0 : (const float*)cT,
            cT, out, hT, flags, t0, Tc);
    }
}

// Round 17
// 2056.895 us; speedup vs baseline: 1.4350x; 1.4350x over previous
//
#include <hip/hip_runtime.h>
#include <cstddef>

#define NB 32
#define NT 512
#define ND 1024
#define NH 1024
#define NG 4096   // 4*NH
#define GRID 256  // 2 groups x 128 blocks (8 units each)

typedef unsigned short ushortT;
typedef __attribute__((ext_vector_type(8))) short short8;   // 8 bf16 = 4 VGPR
typedef __attribute__((ext_vector_type(4))) float f32x4;
typedef __attribute__((ext_vector_type(4))) unsigned uint4v;

#define GLL16(g, l) __builtin_amdgcn_global_load_lds(                      \
    (const __attribute__((address_space(1))) void*)(g),                    \
    (__attribute__((address_space(3))) void*)(l), 16, 0, 0)

__device__ __forceinline__ ushortT f2bf(float f) {
    union { float f; unsigned u; } v; v.f = f;
    unsigned r = v.u + 0x7FFFu + ((v.u >> 16) & 1u);   // RNE
    return (ushortT)(r >> 16);
}
__device__ __forceinline__ float bf2f(ushortT u) {
    union { unsigned u; float f; } v; v.u = (unsigned)u << 16; return v.f;
}

__device__ __forceinline__ float pick4(float a0, float a1, float a2, float a3, int s) {
    float lo = (s & 1) ? a1 : a0;
    float hi = (s & 1) ? a3 : a2;
    return (s & 2) ? hi : lo;
}

__device__ __forceinline__ float fsigmoid(float x) {
    return __builtin_amdgcn_rcpf(1.f + __expf(-x));
}
__device__ __forceinline__ float ftanh(float x) {
    float xc = fminf(fmaxf(x, -15.f), 15.f);
    float e  = __expf(-2.f * xc);
    return (1.f - e) * __builtin_amdgcn_rcpf(1.f + e);
}

// ---------------------------------------------------------------------------
__global__ __launch_bounds__(256) void cast_bf16(const float* __restrict__ src,
                                                 ushortT* __restrict__ dst, int n4)
{
    int i = blockIdx.x * 256 + threadIdx.x;
    if (i < n4) {
        float4 v = ((const float4*)src)[i];
        ushort4 o;
        o.x = f2bf(v.x); o.y = f2bf(v.y); o.z = f2bf(v.z); o.w = f2bf(v.w);
        ((ushort4*)dst)[i] = o;
    }
}

// ---------------------------------------------------------------------------
// transpose + cast: src f32 [1024][4096] -> dst bf16 [4096][1024]
// permute=1 remaps dst row n=(g*1024+j) -> (j>>2)*16 + g*4 + (j&3)
// ---------------------------------------------------------------------------
__global__ __launch_bounds__(256) void transpose_cast(
    const float* __restrict__ src, ushortT* __restrict__ dst, int permute)
{
    __shared__ ushortT tile[64][66];
    const int c0 = blockIdx.x * 64, r0 = blockIdx.y * 64;
    const int cc = threadIdx.x & 63, rq = threadIdx.x >> 6;
    #pragma unroll
    for (int ps = 0; ps < 16; ++ps) {
        int r = ps * 4 + rq;
        tile[cc][r] = f2bf(src[(size_t)(r0 + r) * NG + c0 + cc]);
    }
    __syncthreads();
    #pragma unroll
    for (int ps = 0; ps < 16; ++ps) {
        int cl = ps * 4 + rq;
        int n  = c0 + cl;
        int drow = permute ? ((((n & 1023) >> 2) << 4) | ((n >> 10) << 2) | (n & 3))
                           : n;
        dst[(size_t)drow * 1024 + r0 + cc] = tile[cl][cc];
    }
}

// ---------------------------------------------------------------------------
// xW GEMM, bf16 MFMA, global_load_lds staging.
// Epilogue: bf16 + permuted cols:  xwpb[(trel*NB+b)][perm(n)]
// ---------------------------------------------------------------------------
__global__ __launch_bounds__(256) void gemm_xw_mfma(
    const ushortT* __restrict__ xb,   // [NB*NT][ND] bf16
    const ushortT* __restrict__ wxT,  // [NG][ND]    bf16
    const float* __restrict__ bias,
    ushortT* __restrict__ XWPb,       // [Tc*NB][NG] bf16, permuted cols
    int t0, int Tc, int tcsh)
{
    __shared__ ushortT As[128 * 32];
    __shared__ ushortT Bs[128 * 32];

    const int tid  = threadIdx.x;
    const int lane = tid & 63;
    const int wv   = tid >> 6;
    const int wr   = wv >> 1, wc = wv & 1;
    const int n0   = blockIdx.x * 128;
    const int m0   = blockIdx.y * 128;

    const int c1 = tid, c2 = tid + 256;
    const int rm1 = m0 + (c1 >> 2), rm2 = m0 + (c2 >> 2);
    const int xr1 = ((rm1 >> tcsh) * NT) + t0 + (rm1 & (Tc - 1));
    const int xr2 = ((rm2 >> tcsh) * NT) + t0 + (rm2 & (Tc - 1));
    const ushortT* ap1 = xb + (size_t)xr1 * ND + (c1 & 3) * 8;
    const ushortT* ap2 = xb + (size_t)xr2 * ND + (c2 & 3) * 8;
    const ushortT* bp1 = wxT + (size_t)(n0 + (c1 >> 2)) * ND + (c1 & 3) * 8;
    const ushortT* bp2 = wxT + (size_t)(n0 + (c2 >> 2)) * ND + (c2 & 3) * 8;

    f32x4 acc[4][4];
    #pragma unroll
    for (int m = 0; m < 4; ++m)
        #pragma unroll
        for (int n = 0; n < 4; ++n) acc[m][n] = (f32x4){0.f, 0.f, 0.f, 0.f};

    const int arow_base = (wr * 64 + (lane & 15)) * 32 + (lane >> 4) * 8;
    const int brow_base = (wc * 64 + (lane & 15)) * 32 + (lane >> 4) * 8;

    for (int k0 = 0; k0 < ND; k0 += 32) {
        __syncthreads();
        GLL16(ap1 + k0, &As[c1 * 8]);
        GLL16(ap2 + k0, &As[c2 * 8]);
        GLL16(bp1 + k0, &Bs[c1 * 8]);
        GLL16(bp2 + k0, &Bs[c2 * 8]);
        __syncthreads();
        short8 af[4], bf[4];
        #pragma unroll
        for (int m = 0; m < 4; ++m)
            af[m] = *(const short8*)&As[arow_base + m * 16 * 32];
        #pragma unroll
        for (int n = 0; n < 4; ++n)
            bf[n] = *(const short8*)&Bs[brow_base + n * 16 * 32];
        #pragma unroll
        for (int m = 0; m < 4; ++m)
            #pragma unroll
            for (int n = 0; n < 4; ++n)
                acc[m][n] = __builtin_amdgcn_mfma_f32_16x16x32_bf16(
                    af[m], bf[n], acc[m][n], 0, 0, 0);
    }

    #pragma unroll
    for (int n = 0; n < 4; ++n) {
        int col = n0 + wc * 64 + n * 16 + (lane & 15);
        int pc  = (((col & 1023) >> 2) << 4) | ((col >> 10) << 2) | (col & 3);
        float bs = bias[col];
        #pragma unroll
        for (int m = 0; m < 4; ++m) {
            #pragma unroll
            for (int r = 0; r < 4; ++r) {
                int rm = m0 + wr * 64 + m * 16 + (lane >> 4) * 4 + r;
                int b  = rm >> tcsh, tr = rm & (Tc - 1);
                XWPb[((size_t)tr * NB + b) * NG + pc] = f2bf(acc[m][n][r] + bs);
            }
        }
    }
}

// ---------------------------------------------------------------------------
// Persistent LSTM recurrence: 2 groups (16 batch rows) x 128 blocks (8 units).
// 8 waves = 8 K-splits of 128 units. Wave-autonomous sync (best measured,
// round 9): producer wave: h-store (agent relaxed) -> s_waitcnt vmcnt(0)
// (wave-local) -> lane0 plain-stores flag = trel+1 (no RMW). Consumer wave
// polls ITS 128 producer-wave flags (2/lane, one 8B load) with __all; on
// pass stages its wave-private LDS slice (coalesced). 2 intra-block
// syncthreads (red write/read hazard). 2-buffer h safety: block red-sync
// couples waves => block at step t has seen ALL 1024 flags >= t => everyone
// finished reading h_{t-2} before any h_t store lands.
// ---------------------------------------------------------------------------
__global__ __launch_bounds__(512) void lstm_persist(
    const ushortT* __restrict__ XWPb,  // [Tc*NB][NG] bf16, permuted cols
    const ushortT* __restrict__ whpT,  // [4096][1024] permuted bf16
    unsigned* __restrict__ hb0,        // [32][512] dwords (2xbf16), parity 0
    unsigned* __restrict__ hb1,        // parity 1 (h0 here)
    const float* __restrict__ cinit,
    float* __restrict__ cT,
    float* __restrict__ out,           // [NB][NT][NH] f32
    float* __restrict__ hT,
    unsigned* __restrict__ flags,      // [2][1024], zeroed per launch
    int t0, int Tc)
{
    __shared__ ushortT hs[8 * 2048];   // 32 KB: 8 wave-private 4KB K-slices
    __shared__ float  red[16 * 272];   // 17.4 KB: K-split C partials

    const int tid  = threadIdx.x;
    const int lane = tid & 63;
    const int wv   = tid >> 6;          // K-split 0..7 (units [128wv,128wv+128))
    const int grp  = blockIdx.x & 1;
    const int s    = blockIdx.x >> 1;   // 0..127

    const int lo = lane & 15;
    const int hi = lane >> 4;

    // reduction/activation roles
    const int rrow  = tid >> 5;         // 0..15 (wave wv handles rows 2wv,2wv+1)
    const int col32 = tid & 31;
    const int rct   = col32 >> 4, rc16 = col32 & 15;
    const int gq    = (col32 >> 2) & 3;
    const int uu    = (col32 >> 4) * 4 + (col32 & 3);   // unit 0..7
    const int j     = s * 8 + uu;
    const int brow  = grp * 16 + rrow;

    // Wh register residency: Bf[ct][ks], 32 VGPR
    short8 Bf[2][4];
    #pragma unroll
    for (int ct = 0; ct < 2; ++ct)
        #pragma unroll
        for (int ks = 0; ks < 4; ++ks)
            Bf[ct][ks] = *(const short8*)(whpT
                + (size_t)(s * 32 + ct * 16 + lo) * NH + wv * 128 + ks * 32 + hi * 8);

    float creg = cinit[(size_t)brow * NH + j];

    unsigned* const gf = flags + grp * 1024;
    // wave wv polls producer-wave flags [128*wv, 128*wv+128): 2 per lane (8B)
    const unsigned long long* fp =
        (const unsigned long long*)(gf + 128 * wv + 2 * lane);

    // prefetch first step's xW (bf16)
    ushortT xvr = XWPb[(size_t)brow * NG + s * 32 + col32];

    const int tend = t0 + Tc;
    for (int t = t0; t < tend; ++t) {
        const int trel = t - t0;
        const unsigned* hR = ((t & 1) ? hb0 : hb1) + grp * 8192;  // h_{t-1}
        unsigned*       hW = ((t & 1) ? hb1 : hb0) + grp * 8192;  // h_t

        // wave-autonomous wait for this wave's producers
        if (trel) {
            const unsigned tgt = (unsigned)trel;
            int it = 0;
            for (;;) {
                unsigned long long v = __hip_atomic_load(
                    fp, __ATOMIC_RELAXED, __HIP_MEMORY_SCOPE_AGENT);
                bool ok = ((unsigned)v >= tgt) && ((unsigned)(v >> 32) >= tgt);
                if (__all(ok) || ++it > (1 << 16)) break;
            }
        }

        // stage own K-slice (16 rows x 128 units) -> wave-private LDS slice
        #pragma unroll
        for (int u = 0; u < 4; ++u) {
            int cc  = lane + u * 64;            // 0..255: 16B chunk of slice
            int row = cc >> 4, seg = cc & 15;
            const unsigned long long* sp =
                (const unsigned long long*)(hR + row * 512 + wv * 64 + seg * 4);
            unsigned long long v0 = __hip_atomic_load(sp,     __ATOMIC_RELAXED,
                                                      __HIP_MEMORY_SCOPE_AGENT);
            unsigned long long v1 = __hip_atomic_load(sp + 1, __ATOMIC_RELAXED,
                                                      __HIP_MEMORY_SCOPE_AGENT);
            unsigned byte = (unsigned)(wv * 4096 + row * 256)
                          + (((unsigned)seg * 16u) ^ (((unsigned)(row & 7)) << 4));
            *(uint4v*)((char*)hs + byte) =
                (uint4v){(unsigned)v0, (unsigned)(v0 >> 32),
                         (unsigned)v1, (unsigned)(v1 >> 32)};
        }
        float xv = bf2f(xvr);

        // MFMA: 4 A ds_reads feed 2 independent chains (col-tiles)
        f32x4 acc0 = (f32x4){0.f, 0.f, 0.f, 0.f};
        f32x4 acc1 = (f32x4){0.f, 0.f, 0.f, 0.f};
        #pragma unroll
        for (int ks = 0; ks < 4; ++ks) {
            unsigned ab = (unsigned)(wv * 4096 + lo * 256)
                        + (((unsigned)(ks * 64 + hi * 16)) ^ (((unsigned)(lo & 7)) << 4));
            short8 a = *(const short8*)((char*)hs + ab);
            acc0 = __builtin_amdgcn_mfma_f32_16x16x32_bf16(a, Bf[0][ks], acc0, 0, 0, 0);
            acc1 = __builtin_amdgcn_mfma_f32_16x16x32_bf16(a, Bf[1][ks], acc1, 0, 0, 0);
        }
        #pragma unroll
        for (int r = 0; r < 4; ++r) {
            red[(wv * 2 + 0) * 272 + (hi * 4 + r) * 17 + lo] = acc0[r];
            red[(wv * 2 + 1) * 272 + (hi * 4 + r) * 17 + lo] = acc1[r];
        }
        __syncthreads();

        // reduce 8 K-splits + xW -> own-gate preact
        float g = xv;
        #pragma unroll
        for (int w = 0; w < 8; ++w)
            g += red[(w * 2 + rct) * 272 + rrow * 17 + rc16];
        __syncthreads();   // red reads done -> next step's writes safe

        // gate exchange across lane bits 2-3
        float g4  = __shfl_xor(g, 4);
        float g8  = __shfl_xor(g, 8);
        float g12 = __shfl_xor(g, 12);

        float gi = pick4(g, g4, g8, g12, gq);
        float gf_ = pick4(g, g4, g8, g12, gq ^ 1);
        float gg = pick4(g, g4, g8, g12, gq ^ 2);
        float go = pick4(g, g4, g8, g12, gq ^ 3);

        float iv = fsigmoid(gi);
        float fv = fsigmoid(gf_);
        float gv = ftanh(gg);
        float ov = fsigmoid(go);
        float cn = fv * creg + iv * gv;
        float hn = ov * ftanh(cn);
        creg = cn;

        float ph = __shfl_xor(hn, 1);   // partner unit (uu^1)
        const bool wl = (gq == 0) && ((col32 & 1) == 0);
        if (wl) {
            unsigned pair = (unsigned)f2bf(hn) | ((unsigned)f2bf(ph) << 16);
            __hip_atomic_store(&hW[rrow * 512 + (j >> 1)], pair,
                               __ATOMIC_RELAXED, __HIP_MEMORY_SCOPE_AGENT);
        }

        if (t != tend - 1) {
            // wave-local drain of h stores, then publish per-wave flag
            asm volatile("s_waitcnt vmcnt(0)" ::: "memory");
            if (lane == 0)
                __hip_atomic_store(&gf[s * 8 + wv], (unsigned)(trel + 1),
                                   __ATOMIC_RELAXED, __HIP_MEMORY_SCOPE_AGENT);
            // off-critical-path: out store + next-step xW prefetch
            if (wl)
                *(float2*)&out[((size_t)brow * NT + t) * NH + j] = make_float2(hn, ph);
            xvr = XWPb[((size_t)(trel + 1) * NB + brow) * NG + s * 32 + col32];
        } else {
            if (wl)
                *(float2*)&out[((size_t)brow * NT + t) * NH + j] = make_float2(hn, ph);
            if (gq == 0) {
                if (t == NT - 1) hT[(size_t)brow * NH + j] = hn;
                cT[(size_t)brow * NH + j] = cn;
            }
        }
    }
}

// ---------------------------------------------------------------------------
extern "C" void kernel_launch(void* const* d_in, const int* in_sizes, int n_in,
                              void* d_out, int out_size, void* d_ws, size_t ws_size,
                              hipStream_t stream) {
    const float* x    = (const float*)d_in[0];
    const float* c0   = (const float*)d_in[1];
    const float* h0   = (const float*)d_in[2];
    const float* Wx   = (const float*)d_in[3];
    const float* Wh   = (const float*)d_in[4];
    const float* bias = (const float*)d_in[5];

    float* out = (float*)d_out;
    float* cT  = out + (size_t)NB * NT * NH;
    float* hT  = cT + (size_t)NB * NH;

    // ws: xb 33.5MB | wxT 8.4MB | whpT 8.4MB | hb0 64KB | hb1 64KB | flags 8KB | xwpb
    ushortT* xb   = (ushortT*)d_ws;
    ushortT* wxT  = xb  + (size_t)NB * NT * ND;
    ushortT* whpT = wxT + (size_t)NG * ND;
    unsigned* hb0 = (unsigned*)(whpT + (size_t)NG * NH);
    unsigned* hb1 = hb0 + NB * NH / 2;
    unsigned* flags = hb1 + NB * NH / 2;
    ushortT* xwpb = (ushortT*)(flags + 2 * 1024);

    const size_t fixed = ((size_t)NB * NT * ND + (size_t)NG * ND + (size_t)NG * NH
                          + 2 * NB * NH) * sizeof(ushortT) + 2 * 1024 * 4 + 256;
    int Tc = 512;
    while (Tc > 4 && fixed + (size_t)NB * Tc * NG * sizeof(ushortT) > ws_size)
        Tc >>= 1;
    int tcsh = 31 - __builtin_clz(Tc);

    cast_bf16<<<(NB * NT * ND / 4 + 255) / 256, 256, 0, stream>>>(x, xb, NB * NT * ND / 4);
    // h0 -> hb1 (parity-1 buffer: hR at t=0)
    cast_bf16<<<(NB * NH / 4 + 255) / 256, 256, 0, stream>>>(h0, (ushortT*)hb1, NB * NH / 4);
    transpose_cast<<<dim3(64, 16), 256, 0, stream>>>(Wx, wxT, 0);
    transpose_cast<<<dim3(64, 16), 256, 0, stream>>>(Wh, whpT, 1);

    for (int t0 = 0; t0 < NT; t0 += Tc) {
        dim3 g(NG / 128, (NB * Tc) / 128);
        gemm_xw_mfma<<<g, 256, 0, stream>>>(xb, wxT, bias, xwpb, t0, Tc, tcsh);
        hipMemsetAsync(flags, 0, 2 * 1024 * sizeof(unsigned), stream);
        lstm_persist<<<GRID, 512, 0, stream>>>(
            xwpb, whpT, hb0, hb1,
            (t0 == 0) ? c0 : (const float*)cT,
            cT, out, hT, flags, t0, Tc);
    }
}